// Round 1
// baseline (172.950 us; speedup 1.0000x reference)
//
#include <hip/hip_runtime.h>

typedef short bf16x8 __attribute__((ext_vector_type(8)));
typedef float f32x4 __attribute__((ext_vector_type(4)));

#define T_SEQ 2048
#define NB 8

__device__ inline unsigned short f2bf(float f) {
  unsigned u = __builtin_bit_cast(unsigned, f);
  u += 0x7FFFu + ((u >> 16) & 1u);   // round-to-nearest-even
  return (unsigned short)(u >> 16);
}
__device__ inline float bf2f(unsigned short h) {
  unsigned u = ((unsigned)h) << 16;
  return __builtin_bit_cast(float, u);
}
__device__ inline f32x4 mfma16(bf16x8 a, bf16x8 b, f32x4 c) {
  return __builtin_amdgcn_mfma_f32_16x16x32_bf16(a, b, c, 0, 0, 0);
}

// ---- pad_mask dtype detection: bool(1B) vs int32(4B) storage -------------
// int32 0/1 little-endian has 1-bytes ONLY at byte%4==0. bool padding runs
// (len<2047) put 1s at other offsets. ones==0 -> both interpretations agree.
__global__ void detect_k(const unsigned char* m, int* flag) {
  __shared__ int ones, bad;
  int tid = threadIdx.x;
  if (tid == 0) { ones = 0; bad = 0; }
  __syncthreads();
  int lo = 0, lb = 0;
  for (int i = tid; i < NB * T_SEQ; i += 256) {
    int v = (m[i] != 0);
    lo += v;
    if (i & 3) lb += v;
  }
  atomicAdd(&ones, lo);
  atomicAdd(&bad, lb);
  __syncthreads();
  if (tid == 0) *flag = (ones > 0 && bad == 0) ? 1 : 0;
}

// lengths[b] = count of unmasked keys (mask is monotone: zeros then ones)
__global__ void lengths_k(const unsigned char* m, const int* flag, int* lengths) {
  int b = blockIdx.x, tid = threadIdx.x;
  int cnt = 0;
  if (*flag) {
    const int* mi = (const int*)m;
    for (int t = tid; t < T_SEQ; t += 256) cnt += (mi[b * T_SEQ + t] == 0);
  } else {
    for (int t = tid; t < T_SEQ; t += 256) cnt += (m[b * T_SEQ + t] == 0);
  }
  for (int off = 32; off >= 1; off >>= 1) cnt += __shfl_xor(cnt, off);
  __shared__ int wsum[4];
  if ((tid & 63) == 0) wsum[tid >> 6] = cnt;
  __syncthreads();
  if (tid == 0) lengths[b] = wsum[0] + wsum[1] + wsum[2] + wsum[3];
}

// WT[mi][n][k] (bf16) = W_mi[k][n]  -- so B-frags read 16B contiguous k-runs
__global__ void wt_k(const float* Wq, const float* Wk, const float* Wv,
                     unsigned short* wt) {
  int e = blockIdx.x * 256 + threadIdx.x;
  if (e >= 3 * 64 * 1024) return;
  int mi = e >> 16;
  int rem = e & 65535;
  int kk = rem & 1023, n = rem >> 10;
  const float* W = (mi == 0) ? Wq : (mi == 1) ? Wk : Wv;
  wt[e] = f2bf(W[kk * 64 + n]);
}

// Projection GEMM: X[16384,1024] @ W[1024,64] via bf16 MFMA, no LDS.
// wave = 16 rows x 64 cols; A-frag f32->bf16 cvt from global, B from WT (L2).
__global__ __launch_bounds__(256) void proj_k(
    const float* Q, const float* K, const float* V, const unsigned short* wt,
    unsigned short* qo, unsigned short* ko, unsigned short* vT) {
  int mi = blockIdx.y;
  const float* X = (mi == 0) ? Q : (mi == 1) ? K : V;
  const unsigned short* wtm = wt + mi * 65536;
  int w = threadIdx.x >> 6, lane = threadIdx.x & 63;
  int lane15 = lane & 15, g = lane >> 4;
  int r0 = blockIdx.x * 64 + w * 16;
  int row = r0 + lane15;
  f32x4 acc[4];
#pragma unroll
  for (int i = 0; i < 4; ++i) acc[i] = 0;
  const float4* xr = (const float4*)(X + (size_t)row * 1024);
  for (int ks = 0; ks < 32; ++ks) {
    int kbase = ks * 32 + g * 8;
    float4 xa = xr[kbase / 4];
    float4 xb = xr[kbase / 4 + 1];
    bf16x8 a;
    a[0] = (short)f2bf(xa.x); a[1] = (short)f2bf(xa.y);
    a[2] = (short)f2bf(xa.z); a[3] = (short)f2bf(xa.w);
    a[4] = (short)f2bf(xb.x); a[5] = (short)f2bf(xb.y);
    a[6] = (short)f2bf(xb.z); a[7] = (short)f2bf(xb.w);
#pragma unroll
    for (int nt = 0; nt < 4; ++nt) {
      const bf16x8* wrow =
          (const bf16x8*)(wtm + (size_t)(nt * 16 + lane15) * 1024);
      bf16x8 bfr = wrow[ks * 4 + g];
      acc[nt] = mfma16(a, bfr, acc[nt]);
    }
  }
  // D layout: col = lane&15, row = g*4 + vv  (m89-verified)
#pragma unroll
  for (int nt = 0; nt < 4; ++nt)
#pragma unroll
    for (int vv = 0; vv < 4; ++vv) {
      int rr = r0 + g * 4 + vv;
      int c = nt * 16 + lane15;
      float val = acc[nt][vv];
      if (mi == 0) {
        qo[(size_t)rr * 64 + c] = f2bf(val * 0.03125f);  // fold C^-0.5
      } else if (mi == 1) {
        ko[(size_t)rr * 64 + c] = f2bf(val);
      } else {
        int bb = rr >> 11, tt = rr & 2047;
        vT[((size_t)bb * 64 + c) * T_SEQ + tt] = f2bf(val);
      }
    }
}

// vmean[b][d] = mean over all T of v[b][t][d]  (one wave per (b,d))
__global__ void vmean_k(const unsigned short* vT, float* vmean) {
  int wid = blockIdx.x * 4 + (threadIdx.x >> 6);
  int lane = threadIdx.x & 63;
  const bf16x8* r = (const bf16x8*)vT + (size_t)wid * 256;
  float s = 0.f;
#pragma unroll
  for (int c = 0; c < 4; ++c) {
    bf16x8 vv = r[c * 64 + lane];
#pragma unroll
    for (int i = 0; i < 8; ++i) s += bf2f((unsigned short)vv[i]);
  }
  for (int off = 32; off >= 1; off >>= 1) s += __shfl_xor(s, off);
  if (lane == 0) vmean[wid] = s * (1.0f / T_SEQ);
}

#define NEGB (-1e30f)

// Flash attention: wave = 16 q-rows, key tiles of 32.
__global__ __launch_bounds__(256) void attn_k(
    const unsigned short* q, const unsigned short* k, const unsigned short* vT,
    const float* vmean, const int* lengths, float* Out) {
  __shared__ unsigned short pLds[4][16][40];  // +8 pad: bank spread, 16B rows
  int b = blockIdx.y;
  int t0 = blockIdx.x * 64;
  int w = threadIdx.x >> 6, lane = threadIdx.x & 63;
  int lane15 = lane & 15, g = lane >> 4;
  int t_base = t0 + w * 16;

  // q A-frags: row = lane&15, k-idx = g*8+i (contig d)
  const bf16x8* qrow =
      (const bf16x8*)(q + ((size_t)b * T_SEQ + t_base + lane15) * 64);
  bf16x8 aq0 = qrow[g];      // d 0..31
  bf16x8 aq1 = qrow[4 + g];  // d 32..63

  f32x4 o[4];
  float m[4], l[4];
#pragma unroll
  for (int i = 0; i < 4; ++i) { o[i] = 0; m[i] = NEGB; l[i] = 0.f; }

  const bf16x8* kch = (const bf16x8*)k + (size_t)b * T_SEQ * 8;
  const bf16x8* vch = (const bf16x8*)vT + (size_t)b * 64 * 256;
  int smax = t_base + 15;

  for (int s0 = 0; s0 <= smax; s0 += 32) {
    f32x4 sa[2];
#pragma unroll
    for (int h = 0; h < 2; ++h) {
      int srow = s0 + h * 16 + lane15;
      f32x4 z; z = 0;
      bf16x8 kb0 = kch[srow * 8 + g];
      bf16x8 kb1 = kch[srow * 8 + 4 + g];
      z = mfma16(aq0, kb0, z);
      z = mfma16(aq1, kb1, z);
      sa[h] = z;
    }
    // online softmax; S rows live in 16-lane groups (col=lane&15)
#pragma unroll
    for (int vv = 0; vv < 4; ++vv) {
      int t = t_base + g * 4 + vv;
      float v0 = (s0 + lane15 <= t) ? sa[0][vv] : NEGB;
      float v1 = (s0 + 16 + lane15 <= t) ? sa[1][vv] : NEGB;
      float rm = fmaxf(v0, v1);
#pragma unroll
      for (int off = 8; off >= 1; off >>= 1) rm = fmaxf(rm, __shfl_xor(rm, off));
      float mn = fmaxf(m[vv], rm);
      float corr = __expf(m[vv] - mn);  // 0 on first tile, 1 on masked tiles
      float p0 = __expf(v0 - mn);
      float p1 = __expf(v1 - mn);
      float rs = p0 + p1;
#pragma unroll
      for (int off = 8; off >= 1; off >>= 1) rs += __shfl_xor(rs, off);
      l[vv] = l[vv] * corr + rs;
      m[vv] = mn;
#pragma unroll
      for (int nt = 0; nt < 4; ++nt) o[nt][vv] *= corr;
      pLds[w][g * 4 + vv][lane15] = f2bf(p0);
      pLds[w][g * 4 + vv][16 + lane15] = f2bf(p1);
    }
    // P A-frag: row = lane&15, keys g*8..g*8+7 (wave-local LDS round trip)
    bf16x8 ap = *(const bf16x8*)&pLds[w][lane15][g * 8];
#pragma unroll
    for (int nt = 0; nt < 4; ++nt) {
      bf16x8 bv = vch[((size_t)(nt * 16 + lane15)) * 256 + s0 / 8 + g];
      o[nt] = mfma16(ap, bv, o[nt]);
    }
  }

  int len = lengths[b];
#pragma unroll
  for (int nt = 0; nt < 4; ++nt)
#pragma unroll
    for (int vv = 0; vv < 4; ++vv) {
      int t = t_base + g * 4 + vv;
      int c = nt * 16 + lane15;
      float val = o[nt][vv] / l[vv];
      if (t >= len) val = vmean[b * 64 + c];  // padded query row -> mean(v)
      Out[((size_t)b * T_SEQ + t) * 64 + c] = val;
    }
}

extern "C" void kernel_launch(void* const* d_in, const int* in_sizes, int n_in,
                              void* d_out, int out_size, void* d_ws,
                              size_t ws_size, hipStream_t stream) {
  const float* V = (const float*)d_in[0];
  const float* K = (const float*)d_in[1];
  const float* Q = (const float*)d_in[2];
  const float* Wq = (const float*)d_in[3];
  const float* Wk = (const float*)d_in[4];
  const float* Wv = (const float*)d_in[5];
  const unsigned char* mask = (const unsigned char*)d_in[6];
  float* O = (float*)d_out;
  char* ws = (char*)d_ws;

  // ws layout (all 16B aligned): WT | q | k | vT | vmean | lengths | flag
  unsigned short* wt = (unsigned short*)(ws);                    // 384 KiB
  unsigned short* qb = (unsigned short*)(ws + 393216);           // 2 MiB
  unsigned short* kb = (unsigned short*)(ws + 393216 + 2097152); // 2 MiB
  unsigned short* vT = (unsigned short*)(ws + 393216 + 2 * 2097152); // 2 MiB
  float* vmean = (float*)(ws + 393216 + 3 * 2097152);            // 2 KiB
  int* lengths = (int*)(ws + 393216 + 3 * 2097152 + 2048);
  int* flag = lengths + 8;

  detect_k<<<1, 256, 0, stream>>>(mask, flag);
  lengths_k<<<NB, 256, 0, stream>>>(mask, flag, lengths);
  wt_k<<<768, 256, 0, stream>>>(Wq, Wk, Wv, wt);
  proj_k<<<dim3(256, 3), 256, 0, stream>>>(Q, K, V, wt, qb, kb, vT);
  vmean_k<<<128, 256, 0, stream>>>(vT, vmean);
  attn_k<<<dim3(32, NB), 256, 0, stream>>>(qb, kb, vT, vmean, lengths, O);
}

// Round 2
// 124.189 us; speedup vs baseline: 1.3926x; 1.3926x over previous
//
#include <hip/hip_runtime.h>

typedef short bf16x8 __attribute__((ext_vector_type(8)));
typedef float f32x4 __attribute__((ext_vector_type(4)));

#define T_SEQ 2048
#define NB 8
#define NEGB (-1e30f)

__device__ inline unsigned short f2bf(float f) {
  unsigned u = __builtin_bit_cast(unsigned, f);
  u += 0x7FFFu + ((u >> 16) & 1u);   // round-to-nearest-even
  return (unsigned short)(u >> 16);
}
__device__ inline float bf2f(unsigned short h) {
  unsigned u = ((unsigned)h) << 16;
  return __builtin_bit_cast(float, u);
}
__device__ inline f32x4 mfma16(bf16x8 a, bf16x8 b, f32x4 c) {
  return __builtin_amdgcn_mfma_f32_16x16x32_bf16(a, b, c, 0, 0, 0);
}
__device__ inline bf16x8 pack8(float4 a, float4 b) {
  bf16x8 r;
  r[0] = (short)f2bf(a.x); r[1] = (short)f2bf(a.y);
  r[2] = (short)f2bf(a.z); r[3] = (short)f2bf(a.w);
  r[4] = (short)f2bf(b.x); r[5] = (short)f2bf(b.y);
  r[6] = (short)f2bf(b.z); r[7] = (short)f2bf(b.w);
  return r;
}

// ---- pad_mask dtype detection: bool(1B) vs int32(4B) storage -------------
__global__ void detect_k(const unsigned char* m, int* flag) {
  __shared__ int ones, bad;
  int tid = threadIdx.x;
  if (tid == 0) { ones = 0; bad = 0; }
  __syncthreads();
  int lo = 0, lb = 0;
  for (int i = tid; i < NB * T_SEQ; i += 256) {
    int v = (m[i] != 0);
    lo += v;
    if (i & 3) lb += v;
  }
  atomicAdd(&ones, lo);
  atomicAdd(&bad, lb);
  __syncthreads();
  if (tid == 0) *flag = (ones > 0 && bad == 0) ? 1 : 0;
}

__global__ void lengths_k(const unsigned char* m, const int* flag, int* lengths) {
  int b = blockIdx.x, tid = threadIdx.x;
  int cnt = 0;
  if (*flag) {
    const int* mi = (const int*)m;
    for (int t = tid; t < T_SEQ; t += 256) cnt += (mi[b * T_SEQ + t] == 0);
  } else {
    for (int t = tid; t < T_SEQ; t += 256) cnt += (m[b * T_SEQ + t] == 0);
  }
  for (int off = 32; off >= 1; off >>= 1) cnt += __shfl_xor(cnt, off);
  __shared__ int wsum[4];
  if ((tid & 63) == 0) wsum[tid >> 6] = cnt;
  __syncthreads();
  if (tid == 0) lengths[b] = wsum[0] + wsum[1] + wsum[2] + wsum[3];
}

// WT[mi][n][k] (bf16) = W_mi[k][n]
__global__ void wt_k(const float* Wq, const float* Wk, const float* Wv,
                     unsigned short* wt) {
  int e = blockIdx.x * 256 + threadIdx.x;
  if (e >= 3 * 64 * 1024) return;
  int mi = e >> 16;
  int rem = e & 65535;
  int kk = rem & 1023, n = rem >> 10;
  const float* W = (mi == 0) ? Wq : (mi == 1) ? Wk : Wv;
  wt[e] = f2bf(W[kk * 64 + n]);
}

// Projection GEMM, LDS-staged, coalesced streaming loads.
// Block: 4 waves, 64 rows x 64 cols. BK=64 chunks, XOR-swizzled LDS tiles.
__global__ __launch_bounds__(256) void proj_k(
    const float* Q, const float* K, const float* V, const unsigned short* wt,
    unsigned short* qo, unsigned short* ko, unsigned short* vTb) {
  __shared__ unsigned short xs[64 * 64];   // A tile bf16, swizzled
  __shared__ unsigned short wss[64 * 64];  // B tile bf16, swizzled
  int mi = blockIdx.y;
  const float* X = (mi == 0) ? Q : (mi == 1) ? K : V;
  const unsigned short* wtm = wt + mi * 65536;
  int tid = threadIdx.x;
  int w = tid >> 6, lane = tid & 63, l15 = lane & 15, g = lane >> 4;
  int r0b = blockIdx.x * 64;
  int lr = tid >> 3;   // 0..31
  int e8 = tid & 7;    // 8-element column block
  const float* xrow0 = X + (size_t)(r0b + lr) * 1024 + e8 * 8;
  const float* xrow1 = X + (size_t)(r0b + lr + 32) * 1024 + e8 * 8;
  const unsigned short* wrow0 = wtm + (size_t)lr * 1024 + e8 * 8;
  const unsigned short* wrow1 = wtm + (size_t)(lr + 32) * 1024 + e8 * 8;
  int cbase = (e8 ^ (lr & 7)) * 8;  // swizzled element col (same for lr, lr+32)

  f32x4 acc[4];
#pragma unroll
  for (int i = 0; i < 4; ++i) acc[i] = 0;

  // prefetch chunk 0
  float4 xa0 = *(const float4*)(xrow0);
  float4 xa1 = *(const float4*)(xrow0 + 4);
  float4 xb0 = *(const float4*)(xrow1);
  float4 xb1 = *(const float4*)(xrow1 + 4);
  bf16x8 w0 = *(const bf16x8*)(wrow0);
  bf16x8 w1 = *(const bf16x8*)(wrow1);

  for (int kc = 0; kc < 16; ++kc) {
    __syncthreads();  // previous chunk's compute done
    *(bf16x8*)&xs[lr * 64 + cbase] = pack8(xa0, xa1);
    *(bf16x8*)&xs[(lr + 32) * 64 + cbase] = pack8(xb0, xb1);
    *(bf16x8*)&wss[lr * 64 + cbase] = w0;
    *(bf16x8*)&wss[(lr + 32) * 64 + cbase] = w1;
    if (kc < 15) {  // issue next chunk's loads; in flight across compute
      int c = (kc + 1) * 64;
      xa0 = *(const float4*)(xrow0 + c);
      xa1 = *(const float4*)(xrow0 + c + 4);
      xb0 = *(const float4*)(xrow1 + c);
      xb1 = *(const float4*)(xrow1 + c + 4);
      w0 = *(const bf16x8*)(wrow0 + c);
      w1 = *(const bf16x8*)(wrow1 + c);
    }
    __syncthreads();
#pragma unroll
    for (int ks = 0; ks < 2; ++ks) {
      int arow = w * 16 + l15;
      bf16x8 a =
          *(const bf16x8*)&xs[arow * 64 + (((ks * 4 + g) ^ (l15 & 7)) * 8)];
#pragma unroll
      for (int nt = 0; nt < 4; ++nt) {
        int brow = nt * 16 + l15;
        bf16x8 bb =
            *(const bf16x8*)&wss[brow * 64 + (((ks * 4 + g) ^ (l15 & 7)) * 8)];
        acc[nt] = mfma16(a, bb, acc[nt]);
      }
    }
  }
  // D layout: col = lane&15, row = g*4 + vv
#pragma unroll
  for (int nt = 0; nt < 4; ++nt)
#pragma unroll
    for (int vv = 0; vv < 4; ++vv) {
      int rr = r0b + w * 16 + g * 4 + vv;
      int c = nt * 16 + l15;
      float val = acc[nt][vv];
      if (mi == 0) {
        qo[(size_t)rr * 64 + c] = f2bf(val * 0.03125f);  // fold C^-0.5
      } else if (mi == 1) {
        ko[(size_t)rr * 64 + c] = f2bf(val);
      } else {
        int bb = rr >> 11, ts = rr & 2047;
        // tile-blocked vT: [b][t/32][d][t%32]
        vTb[(((size_t)bb * 64 + (ts >> 5)) * 64 + c) * 32 + (ts & 31)] =
            f2bf(val);
      }
    }
}

// vmean[b][d] from tile-blocked vT
__global__ void vmean_k(const unsigned short* vTb, float* vmean) {
  int b = blockIdx.x, tid = threadIdx.x;
  int k8 = tid & 3;   // which 8-wide kk block
  int d = tid >> 2;   // 0..63
  const unsigned short* base = vTb + (size_t)b * 131072;
  float s = 0.f;
  for (int tt = 0; tt < 64; ++tt) {
    bf16x8 v = *(const bf16x8*)&base[(tt * 64 + d) * 32 + k8 * 8];
#pragma unroll
    for (int i = 0; i < 8; ++i) s += bf2f((unsigned short)v[i]);
  }
  s += __shfl_xor(s, 1);
  s += __shfl_xor(s, 2);
  if (k8 == 0) vmean[b * 64 + d] = s * (1.0f / T_SEQ);
}

// Flash attention: block = 1024 threads = 16 waves = 4 key-chunks x 4 row-groups.
// Wave (j,r): q-rows [t0+16r, +16), keys = contiguous tile-chunk j; LDS merge.
__global__ __launch_bounds__(1024) void attn_k(
    const unsigned short* q, const unsigned short* k, const unsigned short* vTb,
    const float* vmean, const int* lengths, float* Out) {
  __shared__ unsigned short pL[16][16][40];       // per-wave P round-trip
  __shared__ unsigned short oP[4][4][16][64];     // bf16 partial O [j][r][row][col]
  __shared__ float mP[4][4][16], lP[4][4][16];
  int b = blockIdx.y;
  int t0 = blockIdx.x * 64;
  int tid = threadIdx.x;
  int w = tid >> 6, lane = tid & 63;
  int j = w >> 2, r = w & 3;
  int l15 = lane & 15, g = lane >> 4;
  int t_base = t0 + r * 16;

  const bf16x8* qrow =
      (const bf16x8*)(q + ((size_t)b * T_SEQ + t_base + l15) * 64);
  bf16x8 aq0 = qrow[g];
  bf16x8 aq1 = qrow[4 + g];

  f32x4 o[4];
  float m[4], l[4];
#pragma unroll
  for (int i = 0; i < 4; ++i) { o[i] = 0; m[i] = NEGB; l[i] = 0.f; }

  const bf16x8* kch = (const bf16x8*)k + (size_t)b * T_SEQ * 8;
  const unsigned short* vch = vTb + (size_t)b * 131072;

  // balanced contiguous tile-chunks over this block's NT tiles
  int NT = (t0 + 64) >> 5;
  int qn = NT >> 2, rem = NT & 3;
  int start = j * qn + (j < rem ? j : rem);
  int end = start + qn + (j < rem ? 1 : 0);
  int capw = ((t_base + 15) >> 5) + 1;  // rows all masked past this tile
  if (end > capw) end = capw;

  for (int tt = start; tt < end; ++tt) {
    int s0 = tt * 32;
    f32x4 sa0, sa1;
    sa0 = 0; sa1 = 0;
    bf16x8 kb00 = kch[(size_t)(s0 + l15) * 8 + g];
    bf16x8 kb01 = kch[(size_t)(s0 + l15) * 8 + 4 + g];
    bf16x8 kb10 = kch[(size_t)(s0 + 16 + l15) * 8 + g];
    bf16x8 kb11 = kch[(size_t)(s0 + 16 + l15) * 8 + 4 + g];
    sa0 = mfma16(aq0, kb00, sa0);
    sa0 = mfma16(aq1, kb01, sa0);
    sa1 = mfma16(aq0, kb10, sa1);
    sa1 = mfma16(aq1, kb11, sa1);
#pragma unroll
    for (int vv = 0; vv < 4; ++vv) {
      int t = t_base + g * 4 + vv;
      float v0 = (s0 + l15 <= t) ? sa0[vv] : NEGB;
      float v1 = (s0 + 16 + l15 <= t) ? sa1[vv] : NEGB;
      float rm = fmaxf(v0, v1);
#pragma unroll
      for (int off = 8; off >= 1; off >>= 1)
        rm = fmaxf(rm, __shfl_xor(rm, off));
      float mn = fmaxf(m[vv], rm);
      float corr = __expf(m[vv] - mn);          // 1 if both NEGB (l=0, o=0: ok)
      float p0 = (v0 == NEGB) ? 0.f : __expf(v0 - mn);  // guard all-masked tile
      float p1 = (v1 == NEGB) ? 0.f : __expf(v1 - mn);
      float rs = p0 + p1;
#pragma unroll
      for (int off = 8; off >= 1; off >>= 1) rs += __shfl_xor(rs, off);
      l[vv] = l[vv] * corr + rs;
      m[vv] = mn;
#pragma unroll
      for (int nt = 0; nt < 4; ++nt) o[nt][vv] *= corr;
      pL[w][g * 4 + vv][l15] = f2bf(p0);
      pL[w][g * 4 + vv][16 + l15] = f2bf(p1);
    }
    bf16x8 ap = *(const bf16x8*)&pL[w][l15][g * 8];
#pragma unroll
    for (int nt = 0; nt < 4; ++nt) {
      // tile-blocked vT: contiguous-1KB coalesced B-frag
      bf16x8 bv =
          *(const bf16x8*)&vch[((size_t)(tt * 64 + nt * 16 + l15)) * 32 + g * 8];
      o[nt] = mfma16(ap, bv, o[nt]);
    }
  }

  __syncthreads();  // all waves done with pL before partial area reused
#pragma unroll
  for (int nt = 0; nt < 4; ++nt)
#pragma unroll
    for (int vv = 0; vv < 4; ++vv)
      oP[j][r][g * 4 + vv][nt * 16 + l15] = f2bf(o[nt][vv]);
  if (l15 == 0) {
#pragma unroll
    for (int vv = 0; vv < 4; ++vv) {
      mP[j][r][g * 4 + vv] = m[vv];
      lP[j][r][g * 4 + vv] = l[vv];
    }
  }
  __syncthreads();

  if (w < 4) {  // merge wave r=w handles its 16 rows x 64 cols
    int len = lengths[b];
#pragma unroll 4
    for (int row = 0; row < 16; ++row) {
      float m0 = mP[0][w][row], m1 = mP[1][w][row];
      float m2 = mP[2][w][row], m3 = mP[3][w][row];
      float ms = fmaxf(fmaxf(m0, m1), fmaxf(m2, m3));
      float e0 = __expf(m0 - ms), e1 = __expf(m1 - ms);
      float e2 = __expf(m2 - ms), e3 = __expf(m3 - ms);
      float ls = lP[0][w][row] * e0 + lP[1][w][row] * e1 +
                 lP[2][w][row] * e2 + lP[3][w][row] * e3;
      float ov = bf2f(oP[0][w][row][lane]) * e0 +
                 bf2f(oP[1][w][row][lane]) * e1 +
                 bf2f(oP[2][w][row][lane]) * e2 +
                 bf2f(oP[3][w][row][lane]) * e3;
      float val = ov / ls;
      int t = t0 + w * 16 + row;
      if (t >= len) val = vmean[b * 64 + lane];  // padded query row -> mean(v)
      Out[((size_t)b * T_SEQ + t) * 64 + lane] = val;
    }
  }
}

extern "C" void kernel_launch(void* const* d_in, const int* in_sizes, int n_in,
                              void* d_out, int out_size, void* d_ws,
                              size_t ws_size, hipStream_t stream) {
  const float* V = (const float*)d_in[0];
  const float* K = (const float*)d_in[1];
  const float* Q = (const float*)d_in[2];
  const float* Wq = (const float*)d_in[3];
  const float* Wk = (const float*)d_in[4];
  const float* Wv = (const float*)d_in[5];
  const unsigned char* mask = (const unsigned char*)d_in[6];
  float* O = (float*)d_out;
  char* ws = (char*)d_ws;

  unsigned short* wt = (unsigned short*)(ws);                        // 384 KiB
  unsigned short* qb = (unsigned short*)(ws + 393216);               // 2 MiB
  unsigned short* kb = (unsigned short*)(ws + 393216 + 2097152);     // 2 MiB
  unsigned short* vTb = (unsigned short*)(ws + 393216 + 2 * 2097152);// 2 MiB
  float* vmean = (float*)(ws + 393216 + 3 * 2097152);                // 2 KiB
  int* lengths = (int*)(ws + 393216 + 3 * 2097152 + 2048);
  int* flag = lengths + 8;

  detect_k<<<1, 256, 0, stream>>>(mask, flag);
  lengths_k<<<NB, 256, 0, stream>>>(mask, flag, lengths);
  wt_k<<<768, 256, 0, stream>>>(Wq, Wk, Wv, wt);
  proj_k<<<dim3(256, 3), 256, 0, stream>>>(Q, K, V, wt, qb, kb, vTb);
  vmean_k<<<NB, 256, 0, stream>>>(vTb, vmean);
  attn_k<<<dim3(32, NB), 1024, 0, stream>>>(qb, kb, vTb, vmean, lengths, O);
}

// Round 3
// 100.566 us; speedup vs baseline: 1.7198x; 1.2349x over previous
//
#include <hip/hip_runtime.h>

typedef short bf16x8 __attribute__((ext_vector_type(8)));
typedef float f32x4 __attribute__((ext_vector_type(4)));

#define T_SEQ 2048
#define NB 8
#define NEGB (-1e30f)

__device__ inline unsigned short f2bf(float f) {
  unsigned u = __builtin_bit_cast(unsigned, f);
  u += 0x7FFFu + ((u >> 16) & 1u);   // round-to-nearest-even
  return (unsigned short)(u >> 16);
}
__device__ inline float bf2f(unsigned short h) {
  unsigned u = ((unsigned)h) << 16;
  return __builtin_bit_cast(float, u);
}
__device__ inline f32x4 mfma16(bf16x8 a, bf16x8 b, f32x4 c) {
  return __builtin_amdgcn_mfma_f32_16x16x32_bf16(a, b, c, 0, 0, 0);
}
__device__ inline bf16x8 pack8(float4 a, float4 b) {
  bf16x8 r;
  r[0] = (short)f2bf(a.x); r[1] = (short)f2bf(a.y);
  r[2] = (short)f2bf(a.z); r[3] = (short)f2bf(a.w);
  r[4] = (short)f2bf(b.x); r[5] = (short)f2bf(b.y);
  r[6] = (short)f2bf(b.z); r[7] = (short)f2bf(b.w);
  return r;
}
// async 16B global -> LDS (DMA, no VGPR round trip). ldsptr must be
// wave-uniform; HW writes lane l at ldsptr + l*16.
__device__ __forceinline__ void gl_lds16(const void* g, void* l) {
  __builtin_amdgcn_global_load_lds(
      (const __attribute__((address_space(1))) void*)g,
      (__attribute__((address_space(3))) void*)l, 16, 0, 0);
}

// ---- pad_mask dtype detection: bool(1B) vs int32(4B) storage -------------
__global__ void detect_k(const unsigned char* m, int* flag) {
  __shared__ int ones, bad;
  int tid = threadIdx.x;
  if (tid == 0) { ones = 0; bad = 0; }
  __syncthreads();
  int lo = 0, lb = 0;
  for (int i = tid; i < NB * T_SEQ; i += 256) {
    int v = (m[i] != 0);
    lo += v;
    if (i & 3) lb += v;
  }
  atomicAdd(&ones, lo);
  atomicAdd(&bad, lb);
  __syncthreads();
  if (tid == 0) *flag = (ones > 0 && bad == 0) ? 1 : 0;
}

__global__ void lengths_k(const unsigned char* m, const int* flag, int* lengths) {
  int b = blockIdx.x, tid = threadIdx.x;
  int cnt = 0;
  if (*flag) {
    const int* mi = (const int*)m;
    for (int t = tid; t < T_SEQ; t += 256) cnt += (mi[b * T_SEQ + t] == 0);
  } else {
    for (int t = tid; t < T_SEQ; t += 256) cnt += (m[b * T_SEQ + t] == 0);
  }
  for (int off = 32; off >= 1; off >>= 1) cnt += __shfl_xor(cnt, off);
  __shared__ int wsum[4];
  if ((tid & 63) == 0) wsum[tid >> 6] = cnt;
  __syncthreads();
  if (tid == 0) lengths[b] = wsum[0] + wsum[1] + wsum[2] + wsum[3];
}

// WT[mi][n][k] (bf16) = W_mi[k][n]
__global__ void wt_k(const float* Wq, const float* Wk, const float* Wv,
                     unsigned short* wt) {
  int e = blockIdx.x * 256 + threadIdx.x;
  if (e >= 3 * 64 * 1024) return;
  int mi = e >> 16;
  int rem = e & 65535;
  int kk = rem & 1023, n = rem >> 10;
  const float* W = (mi == 0) ? Wq : (mi == 1) ? Wk : Wv;
  wt[e] = f2bf(W[kk * 64 + n]);
}

// Projection GEMM v3: 8 waves, 64x64 tile, BK=64, async global_load_lds
// double-buffer. X staged f32 (cvt at read), W staged bf16. Source-side
// XOR swizzle (blk ^= row&15 / row&7) keeps LDS linear for the DMA and
// fragment ds_read_b128 conflict-free.
__global__ __launch_bounds__(512, 6) void proj_k(
    const float* Q, const float* K, const float* V, const unsigned short* wt,
    unsigned short* qo, unsigned short* ko, unsigned short* vTb) {
  __shared__ float xs[2][4096];          // 16 KB x2: [row][k] f32 (pre-swizzled)
  __shared__ unsigned short wss[2][4096];// 8 KB x2: [n][k] bf16 (pre-swizzled)
  int mi = blockIdx.y;
  const float* X = (mi == 0) ? Q : (mi == 1) ? K : V;
  const unsigned short* wtm = wt + mi * 65536;
  int tid = threadIdx.x;
  int w = tid >> 6, lane = tid & 63, l15 = lane & 15, g = lane >> 4;
  int wr = w >> 1, wc = w & 1;
  int r0b = blockIdx.x * 64;

  // staging addresses (depend on chunk kc, wave-uniform LDS base)
  int segA = w * 2;                       // X: 2 wave-instrs, 1KB each
  int rowA0 = segA * 4 + (lane >> 4);     // rows for instr 0 / 1
  int rowA1 = rowA0 + 4;
  int colA0 = ((lane & 15) ^ (rowA0 & 15)) * 4;
  int colA1 = ((lane & 15) ^ (rowA1 & 15)) * 4;
  const float* srcA0 = X + (size_t)(r0b + rowA0) * 1024 + colA0;
  const float* srcA1 = X + (size_t)(r0b + rowA1) * 1024 + colA1;
  int nW = w * 8 + (lane >> 3);           // W: 1 wave-instr
  int skW = ((lane & 7) ^ (nW & 7)) * 8;
  const unsigned short* srcW = wtm + (size_t)nW * 1024 + skW;

  f32x4 acc[2];
  acc[0] = 0; acc[1] = 0;

#define STAGE(buf, kc2)                                          \
  do {                                                           \
    gl_lds16(srcA0 + (kc2) * 64, &xs[buf][segA * 256]);          \
    gl_lds16(srcA1 + (kc2) * 64, &xs[buf][segA * 256 + 256]);    \
    gl_lds16(srcW + (kc2) * 64, &wss[buf][w * 512]);             \
  } while (0)

  STAGE(0, 0);
  asm volatile("s_waitcnt vmcnt(0)" ::: "memory");
  __syncthreads();

  int arow = wr * 16 + l15;
  const float* xrow_lds;
  for (int kc = 0; kc < 16; ++kc) {
    int cur = kc & 1;
    if (kc < 15) STAGE(cur ^ 1, kc + 1);   // async, in flight across compute
    xrow_lds = &xs[cur][arow * 64];
#pragma unroll
    for (int ks = 0; ks < 2; ++ks) {
      int lb0 = ks * 8 + g * 2;
      float4 fa = *(const float4*)&xrow_lds[(lb0 ^ l15) * 4];
      float4 fb = *(const float4*)&xrow_lds[((lb0 + 1) ^ l15) * 4];
      bf16x8 a = pack8(fa, fb);
#pragma unroll
      for (int nt = 0; nt < 2; ++nt) {
        int nrow = wc * 32 + nt * 16 + l15;
        bf16x8 bb = *(const bf16x8*)
            &wss[cur][nrow * 64 + (((ks * 4 + g) ^ (l15 & 7)) * 8)];
        acc[nt] = mfma16(a, bb, acc[nt]);
      }
    }
    if (kc < 15) {
      asm volatile("s_waitcnt vmcnt(0)" ::: "memory");
      __syncthreads();
    }
  }
#undef STAGE

  // D layout: col = lane&15, row = g*4 + vv
#pragma unroll
  for (int nt = 0; nt < 2; ++nt)
#pragma unroll
    for (int vv = 0; vv < 4; ++vv) {
      int rr = r0b + wr * 16 + g * 4 + vv;
      int c = wc * 32 + nt * 16 + l15;
      float val = acc[nt][vv];
      if (mi == 0) {
        qo[(size_t)rr * 64 + c] = f2bf(val * 0.03125f);  // fold C^-0.5
      } else if (mi == 1) {
        ko[(size_t)rr * 64 + c] = f2bf(val);
      } else {
        int bb = rr >> 11, ts = rr & 2047;
        // tile-blocked vT: [b][t/32][d][t%32]
        vTb[(((size_t)bb * 64 + (ts >> 5)) * 64 + c) * 32 + (ts & 31)] =
            f2bf(val);
      }
    }
}

// vmean[b][d] from tile-blocked vT
__global__ void vmean_k(const unsigned short* vTb, float* vmean) {
  int b = blockIdx.x, tid = threadIdx.x;
  int k8 = tid & 3;
  int d = tid >> 2;
  const unsigned short* base = vTb + (size_t)b * 131072;
  float s = 0.f;
  for (int tt = 0; tt < 64; ++tt) {
    bf16x8 v = *(const bf16x8*)&base[(tt * 64 + d) * 32 + k8 * 8];
#pragma unroll
    for (int i = 0; i < 8; ++i) s += bf2f((unsigned short)v[i]);
  }
  s += __shfl_xor(s, 1);
  s += __shfl_xor(s, 2);
  if (k8 == 0) vmean[b * 64 + d] = s * (1.0f / T_SEQ);
}

// Flash attention v3: 512 threads = 8 waves = 4 key-chunks x 2 row-groups;
// 32 q-rows per block; 512 blocks (2/CU) with work-complementary swizzle.
__global__ __launch_bounds__(512, 4) void attn_k(
    const unsigned short* q, const unsigned short* k, const unsigned short* vTb,
    const float* vmean, const int* lengths, float* Out) {
  __shared__ unsigned short pL[8][16][40];      // per-wave P round-trip
  __shared__ unsigned short oP[4][2][16][64];   // bf16 partial O [j][r][row][col]
  __shared__ float mP[4][2][16], lP[4][2][16];

  // complementary work pairing: blocks id and id+256 get tiles summing ~63
  int id = blockIdx.x;
  int raw = id & 63, b = id >> 6;
  int xx = (raw + 8 * b) & 63;
  int tile = (xx < 32) ? xx : 95 - xx;   // bijective on 0..63
  int t0 = tile * 32;

  int tid = threadIdx.x;
  int w = tid >> 6, lane = tid & 63;
  int j = w >> 1, r = w & 1;
  int l15 = lane & 15, g = lane >> 4;
  int t_base = t0 + r * 16;

  const bf16x8* qrow =
      (const bf16x8*)(q + ((size_t)b * T_SEQ + t_base + l15) * 64);
  bf16x8 aq0 = qrow[g];
  bf16x8 aq1 = qrow[4 + g];

  f32x4 o[4];
  float m[4], l[4];
#pragma unroll
  for (int i = 0; i < 4; ++i) { o[i] = 0; m[i] = NEGB; l[i] = 0.f; }

  const bf16x8* kch = (const bf16x8*)k + (size_t)b * T_SEQ * 8;
  const unsigned short* vch = vTb + (size_t)b * 131072;

  // balanced contiguous tile-chunks over this block's NT key-tiles
  int NT = tile + 1;
  int qn = NT >> 2, rem = NT & 3;
  int start = j * qn + (j < rem ? j : rem);
  int end = start + qn + (j < rem ? 1 : 0);
  int capw = ((t_base + 15) >> 5) + 1;
  if (end > capw) end = capw;

  for (int tt = start; tt < end; ++tt) {
    int s0 = tt * 32;
    f32x4 sa0, sa1;
    sa0 = 0; sa1 = 0;
    bf16x8 kb00 = kch[(size_t)(s0 + l15) * 8 + g];
    bf16x8 kb01 = kch[(size_t)(s0 + l15) * 8 + 4 + g];
    bf16x8 kb10 = kch[(size_t)(s0 + 16 + l15) * 8 + g];
    bf16x8 kb11 = kch[(size_t)(s0 + 16 + l15) * 8 + 4 + g];
    sa0 = mfma16(aq0, kb00, sa0);
    sa0 = mfma16(aq1, kb01, sa0);
    sa1 = mfma16(aq0, kb10, sa1);
    sa1 = mfma16(aq1, kb11, sa1);
#pragma unroll
    for (int vv = 0; vv < 4; ++vv) {
      int t = t_base + g * 4 + vv;
      float v0 = (s0 + l15 <= t) ? sa0[vv] : NEGB;
      float v1 = (s0 + 16 + l15 <= t) ? sa1[vv] : NEGB;
      float rm = fmaxf(v0, v1);
#pragma unroll
      for (int off = 8; off >= 1; off >>= 1)
        rm = fmaxf(rm, __shfl_xor(rm, off));
      float mn = fmaxf(m[vv], rm);
      float corr = __expf(m[vv] - mn);
      float p0 = (v0 == NEGB) ? 0.f : __expf(v0 - mn);  // all-masked tile guard
      float p1 = (v1 == NEGB) ? 0.f : __expf(v1 - mn);
      float rs = p0 + p1;
#pragma unroll
      for (int off = 8; off >= 1; off >>= 1) rs += __shfl_xor(rs, off);
      l[vv] = l[vv] * corr + rs;
      m[vv] = mn;
#pragma unroll
      for (int nt = 0; nt < 4; ++nt) o[nt][vv] *= corr;
      pL[w][g * 4 + vv][l15] = f2bf(p0);
      pL[w][g * 4 + vv][16 + l15] = f2bf(p1);
    }
    bf16x8 ap = *(const bf16x8*)&pL[w][l15][g * 8];
#pragma unroll
    for (int nt = 0; nt < 4; ++nt) {
      bf16x8 bv =
          *(const bf16x8*)&vch[((size_t)(tt * 64 + nt * 16 + l15)) * 32 + g * 8];
      o[nt] = mfma16(ap, bv, o[nt]);
    }
  }

  __syncthreads();
#pragma unroll
  for (int nt = 0; nt < 4; ++nt)
#pragma unroll
    for (int vv = 0; vv < 4; ++vv)
      oP[j][r][g * 4 + vv][nt * 16 + l15] = f2bf(o[nt][vv]);
  if (l15 == 0) {
#pragma unroll
    for (int vv = 0; vv < 4; ++vv) {
      mP[j][r][g * 4 + vv] = m[vv];
      lP[j][r][g * 4 + vv] = l[vv];
    }
  }
  __syncthreads();

  if (w < 2) {  // merge wave r=w: 16 rows x 64 cols, 4-way j-merge
    int len = lengths[b];
#pragma unroll 4
    for (int row = 0; row < 16; ++row) {
      float m0 = mP[0][w][row], m1 = mP[1][w][row];
      float m2 = mP[2][w][row], m3 = mP[3][w][row];
      float ms = fmaxf(fmaxf(m0, m1), fmaxf(m2, m3));
      float e0 = __expf(m0 - ms), e1 = __expf(m1 - ms);
      float e2 = __expf(m2 - ms), e3 = __expf(m3 - ms);
      float ls = lP[0][w][row] * e0 + lP[1][w][row] * e1 +
                 lP[2][w][row] * e2 + lP[3][w][row] * e3;
      float ov = bf2f(oP[0][w][row][lane]) * e0 +
                 bf2f(oP[1][w][row][lane]) * e1 +
                 bf2f(oP[2][w][row][lane]) * e2 +
                 bf2f(oP[3][w][row][lane]) * e3;
      float val = ov / ls;
      int t = t0 + w * 16 + row;
      if (t >= len) val = vmean[b * 64 + lane];  // padded query row -> mean(v)
      Out[((size_t)b * T_SEQ + t) * 64 + lane] = val;
    }
  }
}

extern "C" void kernel_launch(void* const* d_in, const int* in_sizes, int n_in,
                              void* d_out, int out_size, void* d_ws,
                              size_t ws_size, hipStream_t stream) {
  const float* V = (const float*)d_in[0];
  const float* K = (const float*)d_in[1];
  const float* Q = (const float*)d_in[2];
  const float* Wq = (const float*)d_in[3];
  const float* Wk = (const float*)d_in[4];
  const float* Wv = (const float*)d_in[5];
  const unsigned char* mask = (const unsigned char*)d_in[6];
  float* O = (float*)d_out;
  char* ws = (char*)d_ws;

  unsigned short* wt = (unsigned short*)(ws);                        // 384 KiB
  unsigned short* qb = (unsigned short*)(ws + 393216);               // 2 MiB
  unsigned short* kb = (unsigned short*)(ws + 393216 + 2097152);     // 2 MiB
  unsigned short* vTb = (unsigned short*)(ws + 393216 + 2 * 2097152);// 2 MiB
  float* vmean = (float*)(ws + 393216 + 3 * 2097152);                // 2 KiB
  int* lengths = (int*)(ws + 393216 + 3 * 2097152 + 2048);
  int* flag = lengths + 8;

  detect_k<<<1, 256, 0, stream>>>(mask, flag);
  lengths_k<<<NB, 256, 0, stream>>>(mask, flag, lengths);
  wt_k<<<768, 256, 0, stream>>>(Wq, Wk, Wv, wt);
  proj_k<<<dim3(256, 3), 512, 0, stream>>>(Q, K, V, wt, qb, kb, vTb);
  vmean_k<<<NB, 256, 0, stream>>>(vTb, vmean);
  attn_k<<<512, 512, 0, stream>>>(qb, kb, vTb, vmean, lengths, O);
}